// Round 9
// baseline (77.495 us; speedup 1.0000x reference)
//
#include <hip/hip_runtime.h>

#define WL 512   // window_len (t and o dims)
#define NV 64    // n_var
#define LR 16    // low rank
#define NB 512   // batch

__device__ __forceinline__ float tanh_fast(float x) {
    // tanh(x) = 1 - 2/(exp(2x)+1); exact at +-inf saturation, ~1e-7 abs err
    float e = __expf(2.0f * x);
    return 1.0f - 2.0f / (e + 1.0f);
}

// K1: tmp[b,k,v] = sum_t tanh(g[v]*x[b,t,v]) * A[t,k]
// grid = 512 (one block per b), block = 1024 threads (16 waves).
// (byte-identical to R7's verified version)
__global__ __launch_bounds__(1024, 8) void k_tmp(
    const float* __restrict__ x, const float* __restrict__ gating,
    const float* __restrict__ A, float* __restrict__ tmp)
{
    __shared__ float red[16 * LR * NV];  // 64 KiB (16 partials x 1024 (k,v))
    const int tid = threadIdx.x;
    const int b = blockIdx.x;

    const int v = tid & 63;
    const int tg = __builtin_amdgcn_readfirstlane(tid >> 6);
    const float g = gating[v];

    float acc[LR];
#pragma unroll
    for (int k = 0; k < LR; ++k) acc[k] = 0.f;

    const float* xb = x + (size_t)b * (WL * NV) + (size_t)tg * 32 * NV + v;
    const float* Abase = A + (size_t)tg * 32 * LR;

#pragma unroll 4
    for (int i = 0; i < 32; ++i) {
        const float x1 = tanh_fast(g * xb[i * NV]);      // 256B/wave, coalesced
        const float* Ar = Abase + i * LR;                // wave-uniform -> s_load
#pragma unroll
        for (int k = 0; k < LR; ++k) acc[k] = fmaf(x1, Ar[k], acc[k]);
    }

#pragma unroll
    for (int k = 0; k < LR; ++k) red[(tg * LR + k) * NV + v] = acc[k];
    __syncthreads();

    {
        const int p = tid;
        float s = 0.f;
#pragma unroll
        for (int t = 0; t < 16; ++t) s += red[t * (LR * NV) + p];
        tmp[(size_t)b * (LR * NV) + p] = s;
    }
}

// K2: out[b,o,v] = x[b,o,v] + bias[o,v] + sum_k tmp[b,k,v]*B[k,o,v]
// grid = (64 b-chunks of 8) x (32 o-tiles of 16), block = 256 (4 waves)
// thread: v = tid&63, wave og = tid>>6 owns o = oTile*16 + og*4 + j, j=0..3
//
// RESIDENCY FIX: rocprof showed VGPR_Count=64 (R6) / 32 (R8) -- always HALF
// the launch_bounds cap, i.e. the allocator never kept the B panel resident
// and re-loaded it from L2 every batch (1.07 GB L2 traffic ~= 31us = K2's
// entire duration; explains why VMEM-count/prefetch/occupancy fixes were
// all null). Two-part fix:
//  (a) launch_bounds(256,2): VGPR cap 256, half-cap heuristic lands ~128,
//      enough for Breg[64]+tr[16]+misc.
//  (b) asm-pin each Breg/breg value after load: an asm-touched VGPR cannot
//      be rematerialized from memory, so residency is structurally forced.
__global__ __launch_bounds__(256, 2) void k_out(
    const float* __restrict__ x, const float* __restrict__ bias,
    const float* __restrict__ Bm, const float* __restrict__ tmp,
    float* __restrict__ out)
{
    const int tid = threadIdx.x;
    const int v = tid & 63;
    const int og = tid >> 6;
    const int o_base = blockIdx.y * 16 + og * 4;
    const int b0 = blockIdx.x * 8;

    float Breg[4][LR];
#pragma unroll
    for (int j = 0; j < 4; ++j) {
        const int o = o_base + j;
#pragma unroll
        for (int k = 0; k < LR; ++k) {
            Breg[j][k] = Bm[((size_t)k * WL + o) * NV + v];  // 256B/wave, coalesced
            asm volatile("" : "+v"(Breg[j][k]));             // force true VGPR residency
        }
    }
    float breg[4];
#pragma unroll
    for (int j = 0; j < 4; ++j) {
        breg[j] = bias[(o_base + j) * NV + v];
        asm volatile("" : "+v"(breg[j]));
    }

    for (int bi = 0; bi < 8; ++bi) {
        const int b = b0 + bi;
        const float* tb = tmp + (size_t)b * (LR * NV) + v;
        float tr[LR];
#pragma unroll
        for (int k = 0; k < LR; ++k) tr[k] = tb[k * NV];     // coalesced 256B/wave
        const float* xb = x + (size_t)b * WL * NV;
        float* ob = out + (size_t)b * WL * NV;
#pragma unroll
        for (int j = 0; j < 4; ++j) {
            const int o = o_base + j;
            float acc = breg[j];
#pragma unroll
            for (int k = 0; k < LR; ++k) acc += tr[k] * Breg[j][k];
            ob[o * NV + v] = xb[o * NV + v] + acc;
        }
    }
}

extern "C" void kernel_launch(void* const* d_in, const int* in_sizes, int n_in,
                              void* d_out, int out_size, void* d_ws, size_t ws_size,
                              hipStream_t stream) {
    const float* x      = (const float*)d_in[0];  // [512,512,64,1]
    const float* gating = (const float*)d_in[1];  // [64]
    const float* bias   = (const float*)d_in[2];  // [512,64]
    const float* A      = (const float*)d_in[3];  // [512,16]
    const float* Bm     = (const float*)d_in[4];  // [16,512,64]
    float* out = (float*)d_out;
    float* tmp = (float*)d_ws;                    // 2 MiB scratch ([b,k,v])

    k_tmp<<<NB, 1024, 0, stream>>>(x, gating, A, tmp);
    k_out<<<dim3(64, 32), 256, 0, stream>>>(x, bias, Bm, tmp, out);
}

// Round 10
// 46.995 us; speedup vs baseline: 1.6490x; 1.6490x over previous
//
#include <hip/hip_runtime.h>

#define WL 512   // window_len (t and o dims)
#define NV 64    // n_var
#define LR 16    // low rank
#define NB 512   // batch

__device__ __forceinline__ float tanh_fast(float x) {
    // tanh(x) = 1 - 2/(exp(2x)+1); exact at +-inf saturation, ~1e-7 abs err
    float e = __expf(2.0f * x);
    return 1.0f - 2.0f / (e + 1.0f);
}

// K1: tmp[b,k,v] = sum_t tanh(g[v]*x[b,t,v]) * A[t,k]
// grid = 512 (one block per b), block = 1024 threads (16 waves).
// (byte-identical to R7's verified 47.85us version)
__global__ __launch_bounds__(1024, 8) void k_tmp(
    const float* __restrict__ x, const float* __restrict__ gating,
    const float* __restrict__ A, float* __restrict__ tmp)
{
    __shared__ float red[16 * LR * NV];  // 64 KiB (16 partials x 1024 (k,v))
    const int tid = threadIdx.x;
    const int b = blockIdx.x;

    const int v = tid & 63;
    const int tg = __builtin_amdgcn_readfirstlane(tid >> 6);
    const float g = gating[v];

    float acc[LR];
#pragma unroll
    for (int k = 0; k < LR; ++k) acc[k] = 0.f;

    const float* xb = x + (size_t)b * (WL * NV) + (size_t)tg * 32 * NV + v;
    const float* Abase = A + (size_t)tg * 32 * LR;

#pragma unroll 4
    for (int i = 0; i < 32; ++i) {
        const float x1 = tanh_fast(g * xb[i * NV]);      // 256B/wave, coalesced
        const float* Ar = Abase + i * LR;                // wave-uniform -> s_load
#pragma unroll
        for (int k = 0; k < LR; ++k) acc[k] = fmaf(x1, Ar[k], acc[k]);
    }

#pragma unroll
    for (int k = 0; k < LR; ++k) red[(tg * LR + k) * NV + v] = acc[k];
    __syncthreads();

    {
        const int p = tid;
        float s = 0.f;
#pragma unroll
        for (int t = 0; t < 16; ++t) s += red[t * (LR * NV) + p];
        tmp[(size_t)b * (LR * NV) + p] = s;
    }
}

// K2: out[b,o,v] = x[b,o,v] + bias[o,v] + sum_k tmp[b,k,v]*B[k,o,v]
// grid = (32 b-chunks of 16) x (16 o-tiles of 32), block = 256 (4 waves)
// thread: v = tid&63; wave w = tid>>6 owns o = oTile*32 + w*8 + {0..7}
//
// OCCUPANCY-PIN FIX: launch_bounds only sets MIN waves/EU; the scheduler
// chases MAX occupancy (8/EU) and budgets ~32-64 VGPR, refetching B every
// batch (88 wave-VMEM per wave-batch = ~37us issue + 1.07GB L2 — the
// measured K2 wall across R2/R8/R9). amdgpu_waves_per_eu(2,2) pins the
// range: budget 256 VGPR, scheduler cannot chase occupancy, so
// Breg[8][16] (128 VGPR) stays genuinely resident. 8 o/thread amortizes
// the 16 tr loads -> 5 wave-VMEM per output row (was ~22).
// tr/x double-buffered with STATIC buffer names (no runtime-indexed arrays).
__global__ __attribute__((amdgpu_flat_work_group_size(256, 256),
                          amdgpu_waves_per_eu(2, 2)))
void k_out(
    const float* __restrict__ x, const float* __restrict__ bias,
    const float* __restrict__ Bm, const float* __restrict__ tmp,
    float* __restrict__ out)
{
    const int tid = threadIdx.x;
    const int v = tid & 63;
    const int w = tid >> 6;                       // wave 0..3
    const int o_base = blockIdx.y * 32 + w * 8;   // wave's 8 o-rows
    const int b0 = blockIdx.x * 16;

    float Breg[8][LR];
#pragma unroll
    for (int j = 0; j < 8; ++j) {
        const int o = o_base + j;
#pragma unroll
        for (int k = 0; k < LR; ++k)
            Breg[j][k] = Bm[((size_t)k * WL + o) * NV + v];  // 256B/wave, coalesced
    }
    float breg[8];
#pragma unroll
    for (int j = 0; j < 8; ++j) breg[j] = bias[(o_base + j) * NV + v];

    float trA[LR], trB[LR], xrA[8], xrB[8];

    // preload b0 into A-buffers
    {
        const float* tb = tmp + (size_t)b0 * (LR * NV) + v;
#pragma unroll
        for (int k = 0; k < LR; ++k) trA[k] = tb[k * NV];
        const float* xb = x + (size_t)b0 * WL * NV;
#pragma unroll
        for (int j = 0; j < 8; ++j) xrA[j] = xb[(o_base + j) * NV + v];
    }

#pragma unroll 1
    for (int bi = 0; bi < 16; bi += 2) {
        const int b = b0 + bi;

        // prefetch b+1 into B-buffers
        {
            const float* tb = tmp + (size_t)(b + 1) * (LR * NV) + v;
#pragma unroll
            for (int k = 0; k < LR; ++k) trB[k] = tb[k * NV];
            const float* xb = x + (size_t)(b + 1) * WL * NV;
#pragma unroll
            for (int j = 0; j < 8; ++j) xrB[j] = xb[(o_base + j) * NV + v];
        }

        // compute b from A-buffers
        {
            float* ob = out + (size_t)b * WL * NV;
#pragma unroll
            for (int j = 0; j < 8; ++j) {
                float acc = breg[j];
#pragma unroll
                for (int k = 0; k < LR; ++k) acc += trA[k] * Breg[j][k];
                ob[(o_base + j) * NV + v] = xrA[j] + acc;
            }
        }

        // prefetch b+2 into A-buffers
        if (bi + 2 < 16) {
            const float* tb = tmp + (size_t)(b + 2) * (LR * NV) + v;
#pragma unroll
            for (int k = 0; k < LR; ++k) trA[k] = tb[k * NV];
            const float* xb = x + (size_t)(b + 2) * WL * NV;
#pragma unroll
            for (int j = 0; j < 8; ++j) xrA[j] = xb[(o_base + j) * NV + v];
        }

        // compute b+1 from B-buffers
        {
            float* ob = out + (size_t)(b + 1) * WL * NV;
#pragma unroll
            for (int j = 0; j < 8; ++j) {
                float acc = breg[j];
#pragma unroll
                for (int k = 0; k < LR; ++k) acc += trB[k] * Breg[j][k];
                ob[(o_base + j) * NV + v] = xrB[j] + acc;
            }
        }
    }
}

extern "C" void kernel_launch(void* const* d_in, const int* in_sizes, int n_in,
                              void* d_out, int out_size, void* d_ws, size_t ws_size,
                              hipStream_t stream) {
    const float* x      = (const float*)d_in[0];  // [512,512,64,1]
    const float* gating = (const float*)d_in[1];  // [64]
    const float* bias   = (const float*)d_in[2];  // [512,64]
    const float* A      = (const float*)d_in[3];  // [512,16]
    const float* Bm     = (const float*)d_in[4];  // [16,512,64]
    float* out = (float*)d_out;
    float* tmp = (float*)d_ws;                    // 2 MiB scratch ([b,k,v])

    k_tmp<<<NB, 1024, 0, stream>>>(x, gating, A, tmp);
    k_out<<<dim3(32, 16), 256, 0, stream>>>(x, bias, Bm, tmp, out);
}